// Round 12
// baseline (156.369 us; speedup 1.0000x reference)
//
#include <hip/hip_runtime.h>

typedef __attribute__((ext_vector_type(8))) short bf16x8;
typedef __attribute__((ext_vector_type(4))) float f32x4;

#define TILE 32

__device__ __forceinline__ unsigned f2bf(float x) {
    unsigned u = __float_as_uint(x);
    return (u + 0x7fffu + ((u >> 16) & 1u)) >> 16;   // RNE f32->bf16
}

// ---- labels: t_hard = argmax(t_label); per-class counts + row lists ----
__global__ void k_prep(const int* __restrict__ slab, const float* __restrict__ tlab,
                       int ns, int N, int C,
                       int* __restrict__ clsrows, int* __restrict__ cnt_src,
                       int* __restrict__ fill) {
    int i = blockIdx.x * 256 + threadIdx.x;
    if (i >= N) return;
    int lab;
    if (i < ns) {
        lab = slab[i];
    } else {
        const float* row = tlab + (size_t)(i - ns) * C;
        float best = row[0];
        lab = 0;
        for (int c = 1; c < C; c++) {
            float v = row[c];
            if (v > best) { best = v; lab = c; }   // strict >: first-max (jnp.argmax)
        }
    }
    if (i < ns) atomicAdd(&cnt_src[lab], 1);
    int pos = atomicAdd(&fill[lab], 1);
    clsrows[(size_t)lab * N + pos] = i;
}

// scan: padded row offsets (32-aligned per present class) + upper-tri tile offsets
__device__ __forceinline__ void scan_offsets2(const int* __restrict__ cnt_src,
                                              const int* __restrict__ fill, int C,
                                              int* proS, int* tpoS, int* tS, int* presS,
                                              int* padTotS, int* nTilesS) {
    if (threadIdx.x < 64) {
        int lane = threadIdx.x;
        int n = (lane < C) ? fill[lane] : 0;
        int nsrc = (lane < C) ? cnt_src[lane] : 0;
        int pres = (nsrc > 0 && (n - nsrc) > 0) ? 1 : 0;
        int T = pres ? (n + TILE - 1) / TILE : 0;
        int prw = T * 32;                 // padded rows
        int t2 = T * (T + 1) / 2;         // upper-triangle tiles
        int sp = prw, st = t2;
        for (int o = 1; o < 64; o <<= 1) {
            int a = __shfl_up(sp, o), b = __shfl_up(st, o);
            if (lane >= o) { sp += a; st += b; }
        }
        if (lane < C) {
            proS[lane] = sp - prw; tpoS[lane] = st - t2;
            tS[lane] = T; presS[lane] = pres;
        }
        if (lane == C - 1) { proS[C] = sp; tpoS[C] = st; *padTotS = sp; *nTilesS = st; }
    }
    __syncthreads();
}

// ---- gather: 16-row panel per block, rows parallel over 4 waves ->
//      fragment-major Xp + sq/sign/sqsum/classum ----
__global__ __launch_bounds__(256) void k_gather(
        const float* __restrict__ src, const float* __restrict__ tgt,
        const int* __restrict__ clsrows,
        const int* __restrict__ cnt_src, const int* __restrict__ fill,
        int ns, int N, int D, int C,
        unsigned short* __restrict__ Xp, float* __restrict__ sqg, float* __restrict__ sgg,
        double* __restrict__ sqsum, float* __restrict__ classum) {
    __shared__ int proS[65], tpoS[65], tS[64], presS[64], padTotS, nTilesS;
    scan_offsets2(cnt_src, fill, C, proS, tpoS, tS, presS, &padTotS, &nTilesS);
    int p = blockIdx.x;
    int s0 = p * 16;
    if (s0 >= padTotS) return;
    int tid = threadIdx.x;
    int lane = tid & 63;
    int wv = tid >> 6;
    int c = __popcll(__ballot((lane < C) && (proS[lane] <= s0))) - 1;
    int n = fill[c];
    int idx0 = s0 - proS[c];

    __shared__ unsigned short Ls[16][2048 + 8];
    __shared__ float classumS[2048];
    __shared__ float sqS[16];
    for (int j = tid; j < 2048; j += 256) classumS[j] = 0.f;

    float cs[4][8];
    #pragma unroll
    for (int it = 0; it < 4; it++)
        #pragma unroll
        for (int j = 0; j < 8; j++) cs[it][j] = 0.f;

    // wave wv handles rows {wv, 4+wv, 8+wv, 12+wv}
    #pragma unroll
    for (int rr = 0; rr < 4; rr++) {
        int r = rr * 4 + wv;
        int idx = idx0 + r;
        bool valid = idx < n;
        int g = valid ? clsrows[(size_t)c * N + idx] : 0;
        const float* row = (g < ns) ? src + (size_t)g * D : tgt + (size_t)(g - ns) * D;
        float a = 0.f;
        #pragma unroll
        for (int it = 0; it < 4; it++) {
            float4 v0 = {0.f, 0.f, 0.f, 0.f}, v1 = v0;
            if (valid) {
                v0 = *(const float4*)(row + it * 512 + lane * 8);
                v1 = *(const float4*)(row + it * 512 + lane * 8 + 4);
            }
            cs[it][0] += v0.x; cs[it][1] += v0.y; cs[it][2] += v0.z; cs[it][3] += v0.w;
            cs[it][4] += v1.x; cs[it][5] += v1.y; cs[it][6] += v1.z; cs[it][7] += v1.w;
            a += v0.x*v0.x + v0.y*v0.y + v0.z*v0.z + v0.w*v0.w
               + v1.x*v1.x + v1.y*v1.y + v1.z*v1.z + v1.w*v1.w;
            uint4 pk;
            pk.x = f2bf(v0.x) | (f2bf(v0.y) << 16);
            pk.y = f2bf(v0.z) | (f2bf(v0.w) << 16);
            pk.z = f2bf(v1.x) | (f2bf(v1.y) << 16);
            pk.w = f2bf(v1.z) | (f2bf(v1.w) << 16);
            *(uint4*)&Ls[r][it * 512 + lane * 8] = pk;
        }
        for (int o = 32; o; o >>= 1) a += __shfl_down(a, o);
        if (lane == 0) sqS[r] = a;
    }
    __syncthreads();   // classumS zero + all cs ready
    #pragma unroll
    for (int it = 0; it < 4; it++)
        #pragma unroll
        for (int j = 0; j < 8; j++)
            atomicAdd(&classumS[it * 512 + lane * 8 + j], cs[it][j]);
    __syncthreads();
    for (int j = tid; j < 2048; j += 256)
        atomicAdd(&classum[(size_t)c * D + j], classumS[j]);
    if (tid < 16) {
        int idx = idx0 + tid;
        bool valid = idx < n;
        int g = valid ? clsrows[(size_t)c * N + idx] : 0;
        sqg[s0 + tid] = valid ? sqS[tid] : 0.f;
        sgg[s0 + tid] = valid ? ((g < ns) ? 1.f : -1.f) : 0.f;
    }
    if (tid == 0) {
        double tot = 0.0;
        for (int r = 0; r < 16; r++) tot += (double)sqS[r];
        atomicAdd(&sqsum[c], tot);
    }
    // phase 2: fragment-major write  Xp[(p*256 + k8)*128 + pr*8 .. +8]
    int pr = tid & 15, kq = tid >> 4;
    size_t pb = (size_t)p * 32768;    // u16 units per panel (16 rows * 2048)
    for (int o = 0; o < 16; o++) {
        int k8 = kq * 16 + o;
        uint4 val = *(uint4*)&Ls[pr][k8 * 8];
        *(uint4*)(Xp + pb + (size_t)k8 * 128 + pr * 8) = val;
    }
}

// ---- per-class bandwidth from closed form ----
__global__ void k_bw(const float* __restrict__ classum, const double* __restrict__ sqsum,
                     const int* __restrict__ cnt_src, const int* __restrict__ fill,
                     int D, int C, float* __restrict__ invbw) {
    int c = blockIdx.x;
    int tid = threadIdx.x;
    int n = fill[c], nsrc = cnt_src[c];
    int pres = (nsrc > 0 && (n - nsrc) > 0) ? 1 : 0;
    const float* cp = classum + (size_t)c * D;
    double sn = 0.0;
    for (int d = tid; d < D; d += 256) { double v = (double)cp[d]; sn += v * v; }
    for (int o = 32; o; o >>= 1) sn += __shfl_down(sn, o);
    __shared__ double ls[4];
    if ((tid & 63) == 0) ls[tid >> 6] = sn;
    __syncthreads();
    if (tid == 0) {
        double snorm = ls[0] + ls[1] + ls[2] + ls[3];
        double l2 = 2.0 * (double)n * sqsum[c] - 2.0 * snorm;
        double den = (double)n * (double)n - (double)n; if (den < 1.0) den = 1.0;
        double bw = l2 / den / 4.0;          // bw_scale = KERNEL_MUL^(KERNEL_NUM//2)
        bw = pres ? fmax(bw, 1e-20) : 1.0;
        double m = 1.0;
        for (int k = 0; k < 5; k++) { invbw[c * 5 + k] = (float)(1.0 / (bw * m)); m *= 2.0; }
    }
}

// ---- fused pair kernel: block = (class, ti<=tj tile); 8 waves split-K; in-block epi ----
__global__ __launch_bounds__(512) void k_pairs(
        const unsigned short* __restrict__ Xp, const float* __restrict__ sqg,
        const float* __restrict__ sgg, const float* __restrict__ invbw,
        const int* __restrict__ cnt_src, const int* __restrict__ fill,
        int N, int D, int C, double* __restrict__ contrib) {
    __shared__ int proS[65], tpoS[65], tS[64], presS[64], padTotS, nTilesS;
    scan_offsets2(cnt_src, fill, C, proS, tpoS, tS, presS, &padTotS, &nTilesS);
    __shared__ float Lp[8 * 4 * 4 * 64];     // [wv][frag][r][lane] = 32 KB
    __shared__ float sqA[32], sgA[32], sqB[32], sgB[32];

    int tid = threadIdx.x, lane = tid & 63, wv = tid >> 6;
    int kgrp = lane >> 4, lr = lane & 15;
    int nTiles = nTilesS;

    for (int job = blockIdx.x; job < nTiles; job += gridDim.x) {
        __syncthreads();                      // protect LDS from previous job
        int c = __popcll(__ballot((lane < C) && (tpoS[lane] <= job))) - 1;
        int t = job - tpoS[c];
        int T = tS[c];
        int ti = 0, rem = t;
        while (rem >= T - ti) { rem -= (T - ti); ti++; }   // upper-triangle decode
        int tj = ti + rem;
        int pbase = proS[c];
        int n = fill[c];
        float wgt = (ti == tj) ? 1.f : 2.f;   // gram symmetry

        if (tid < 32) {
            sqA[tid] = sqg[pbase + ti * 32 + tid];
            sgA[tid] = sgg[pbase + ti * 32 + tid];
        } else if (tid < 64) {
            int j = tid - 32;
            sqB[j] = sqg[pbase + tj * 32 + j];
            sgB[j] = sgg[pbase + tj * 32 + j];
        }

        size_t pA0 = ((size_t)(pbase >> 4) + ti * 2) * 32768;   // u16 units
        size_t pA1 = pA0 + 32768;
        size_t pB0 = ((size_t)(pbase >> 4) + tj * 2) * 32768;
        size_t pB1 = pB0 + 32768;
        int k8base = wv * 32;                 // this wave's K-eighth (256 dims)

        f32x4 a00 = (f32x4){0.f, 0.f, 0.f, 0.f}, a01 = a00, a10 = a00, a11 = a00;
        #pragma unroll
        for (int ks = 0; ks < 8; ks++) {
            size_t off = (size_t)(k8base + ks * 4 + kgrp) * 128 + lr * 8;
            bf16x8 va0 = *(const bf16x8*)(Xp + pA0 + off);
            bf16x8 va1 = *(const bf16x8*)(Xp + pA1 + off);
            bf16x8 vb0 = *(const bf16x8*)(Xp + pB0 + off);
            bf16x8 vb1 = *(const bf16x8*)(Xp + pB1 + off);
            a00 = __builtin_amdgcn_mfma_f32_16x16x32_bf16(va0, vb0, a00, 0, 0, 0);
            a01 = __builtin_amdgcn_mfma_f32_16x16x32_bf16(va0, vb1, a01, 0, 0, 0);
            a10 = __builtin_amdgcn_mfma_f32_16x16x32_bf16(va1, vb0, a10, 0, 0, 0);
            a11 = __builtin_amdgcn_mfma_f32_16x16x32_bf16(va1, vb1, a11, 0, 0, 0);
        }
        #pragma unroll
        for (int r = 0; r < 4; r++) {
            Lp[((wv * 4 + 0) * 4 + r) * 64 + lane] = a00[r];
            Lp[((wv * 4 + 1) * 4 + r) * 64 + lane] = a01[r];
            Lp[((wv * 4 + 2) * 4 + r) * 64 + lane] = a10[r];
            Lp[((wv * 4 + 3) * 4 + r) * 64 + lane] = a11[r];
        }
        __syncthreads();

        float ib0 = invbw[c * 5 + 0], ib1 = invbw[c * 5 + 1], ib2 = invbw[c * 5 + 2];
        float ib3 = invbw[c * 5 + 3], ib4 = invbw[c * 5 + 4];
        int i = tid >> 4;                     // 0..31
        int j0 = (tid & 15) * 2;
        bool vi = (ti * 32 + i) < n;
        float sa = sqA[i], ga = sgA[i];
        float ts = 0.f;
        #pragma unroll
        for (int q = 0; q < 2; q++) {
            int j = j0 + q;
            bool vj = (tj * 32 + j) < n;
            int f = (i >> 4) * 2 + (j >> 4);
            int le = ((i & 15) >> 2) * 16 + (j & 15);   // m89 C/D layout
            int r = i & 3;
            float dot = 0.f;
            #pragma unroll
            for (int w8 = 0; w8 < 8; w8++)
                dot += Lp[((w8 * 4 + f) * 4 + r) * 64 + le];
            if (vi && vj) {
                float D2 = sa + sqB[j] - 2.f * dot;
                float e = expf(-D2 * ib0) + expf(-D2 * ib1) + expf(-D2 * ib2)
                        + expf(-D2 * ib3) + expf(-D2 * ib4);
                ts += ga * sgB[j] * e;
            }
        }
        double ds = (double)(ts * wgt);
        for (int o = 32; o; o >>= 1) ds += __shfl_down(ds, o);
        if (lane == 0) atomicAdd(&contrib[c], ds);
    }
}

__global__ void k_final(const double* __restrict__ contrib,
                        const int* __restrict__ cnt_src, const int* __restrict__ fill,
                        int C, float* __restrict__ out) {
    int c = threadIdx.x;
    double l = 0.0, k = 0.0;
    if (c < C) {
        int n = fill[c], nsrc = cnt_src[c];
        if (nsrc > 0 && (n - nsrc) > 0) {
            double nn = (double)n * (double)n; if (nn < 1.0) nn = 1.0;
            l = contrib[c] / nn; k = 1.0;
        }
    }
    for (int o = 32; o; o >>= 1) { l += __shfl_down(l, o); k += __shfl_down(k, o); }
    if (c == 0) out[0] = (float)(l / k);
}

extern "C" void kernel_launch(void* const* d_in, const int* in_sizes, int n_in,
                              void* d_out, int out_size, void* d_ws, size_t ws_size,
                              hipStream_t stream) {
    const float* src  = (const float*)d_in[0];
    const float* tgt  = (const float*)d_in[1];
    const int*   slab = (const int*)d_in[2];
    const float* tlab = (const float*)d_in[3];
    const int ns = in_sizes[2];
    const int D  = in_sizes[0] / ns;
    const int nt = in_sizes[1] / D;
    const int C  = in_sizes[3] / nt;
    const int N  = ns + nt;
    const int padN = N + 32 * C;            // upper bound on padded slots

    char* w = (char*)d_ws;
    size_t off = 0;
    auto take = [&](size_t bytes) -> char* {
        char* p = w + off;
        off = (off + bytes + 255) & ~(size_t)255;
        return p;
    };
    // --- zero region (memset below) ---
    int*    cnt_src = (int*)take(64 * sizeof(int));
    int*    fill    = (int*)take(64 * sizeof(int));
    double* sqsum   = (double*)take(64 * sizeof(double));
    double* contrib = (double*)take(64 * sizeof(double));
    float*  classum = (float*)take((size_t)C * D * sizeof(float));
    size_t zbytes = off;
    // --- rest ---
    int*            clsrows = (int*)take((size_t)C * N * sizeof(int));
    float*          sqg     = (float*)take((size_t)padN * sizeof(float));
    float*          sgg     = (float*)take((size_t)padN * sizeof(float));
    float*          invbw   = (float*)take((size_t)C * 5 * sizeof(float));
    unsigned short* Xp      = (unsigned short*)take((size_t)padN * D * sizeof(unsigned short));
    (void)n_in; (void)out_size; (void)ws_size;

    hipMemsetAsync(d_ws, 0, zbytes, stream);
    k_prep<<<(N + 255) / 256, 256, 0, stream>>>(slab, tlab, ns, N, C, clsrows, cnt_src, fill);
    k_gather<<<(padN + 15) / 16, 256, 0, stream>>>(src, tgt, clsrows, cnt_src, fill,
                                                   ns, N, D, C, Xp, sqg, sgg, sqsum, classum);
    k_bw<<<C, 256, 0, stream>>>(classum, sqsum, cnt_src, fill, D, C, invbw);
    k_pairs<<<512, 512, 0, stream>>>(Xp, sqg, sgg, invbw, cnt_src, fill, N, D, C, contrib);
    k_final<<<1, 64, 0, stream>>>(contrib, cnt_src, fill, C, (float*)d_out);
}

// Round 13
// 124.260 us; speedup vs baseline: 1.2584x; 1.2584x over previous
//
#include <hip/hip_runtime.h>

typedef __attribute__((ext_vector_type(8))) short bf16x8;
typedef __attribute__((ext_vector_type(4))) float f32x4;

#define TILE 32

__device__ __forceinline__ unsigned f2bf(float x) {
    unsigned u = __float_as_uint(x);
    return (u + 0x7fffu + ((u >> 16) & 1u)) >> 16;   // RNE f32->bf16
}

// ---- labels: t_hard = argmax(t_label); per-class counts + row lists ----
__global__ void k_prep(const int* __restrict__ slab, const float* __restrict__ tlab,
                       int ns, int N, int C,
                       int* __restrict__ clsrows, int* __restrict__ cnt_src,
                       int* __restrict__ fill) {
    int i = blockIdx.x * 256 + threadIdx.x;
    if (i >= N) return;
    int lab;
    if (i < ns) {
        lab = slab[i];
    } else {
        const float* row = tlab + (size_t)(i - ns) * C;
        float best = row[0];
        lab = 0;
        for (int c = 1; c < C; c++) {
            float v = row[c];
            if (v > best) { best = v; lab = c; }   // strict >: first-max (jnp.argmax)
        }
    }
    if (i < ns) atomicAdd(&cnt_src[lab], 1);
    int pos = atomicAdd(&fill[lab], 1);
    clsrows[(size_t)lab * N + pos] = i;
}

// scan: padded row offsets (32-aligned per present class) + upper-tri tile offsets
__device__ __forceinline__ void scan_offsets2(const int* __restrict__ cnt_src,
                                              const int* __restrict__ fill, int C,
                                              int* proS, int* tpoS, int* tS, int* presS,
                                              int* padTotS, int* nTilesS) {
    if (threadIdx.x < 64) {
        int lane = threadIdx.x;
        int n = (lane < C) ? fill[lane] : 0;
        int nsrc = (lane < C) ? cnt_src[lane] : 0;
        int pres = (nsrc > 0 && (n - nsrc) > 0) ? 1 : 0;
        int T = pres ? (n + TILE - 1) / TILE : 0;
        int prw = T * 32;                 // padded rows
        int t2 = T * (T + 1) / 2;         // upper-triangle tiles
        int sp = prw, st = t2;
        for (int o = 1; o < 64; o <<= 1) {
            int a = __shfl_up(sp, o), b = __shfl_up(st, o);
            if (lane >= o) { sp += a; st += b; }
        }
        if (lane < C) {
            proS[lane] = sp - prw; tpoS[lane] = st - t2;
            tS[lane] = T; presS[lane] = pres;
        }
        if (lane == C - 1) { proS[C] = sp; tpoS[C] = st; *padTotS = sp; *nTilesS = st; }
    }
    __syncthreads();
}

// ---- gather: block = (16-row panel, 512-dim chunk); ~17 KB LDS, coalesced ----
__global__ __launch_bounds__(256) void k_gather(
        const float* __restrict__ src, const float* __restrict__ tgt,
        const int* __restrict__ clsrows,
        const int* __restrict__ cnt_src, const int* __restrict__ fill,
        int ns, int N, int D, int C,
        unsigned short* __restrict__ Xp, float* __restrict__ sqg, float* __restrict__ sgg,
        float* __restrict__ classum) {
    __shared__ int proS[65], tpoS[65], tS[64], presS[64], padTotS, nTilesS;
    scan_offsets2(cnt_src, fill, C, proS, tpoS, tS, presS, &padTotS, &nTilesS);
    int p = blockIdx.x;
    int chunk = blockIdx.y;               // 512-dim chunk (0..3)
    int s0 = p * 16;
    if (s0 >= padTotS) return;
    int tid = threadIdx.x;
    int lane = tid & 63;
    int c = __popcll(__ballot((lane < C) && (proS[lane] <= s0))) - 1;
    int n = fill[c];
    int idx0 = s0 - proS[c];
    int cbase = chunk * 512;

    __shared__ unsigned short Ls[16][520];

    // stage 16 rows x 512 dims: r = tid>>4 row, q = tid&15; 8 coalesced float4 per thread
    int r = tid >> 4, q = tid & 15;
    int idx = idx0 + r;
    bool valid = idx < n;
    int g = valid ? clsrows[(size_t)c * N + idx] : 0;
    const float* row = (g < ns) ? src + (size_t)g * D : tgt + (size_t)(g - ns) * D;
    float a = 0.f;
    #pragma unroll
    for (int it = 0; it < 8; it++) {
        int col = it * 64 + q * 4;
        float4 v = {0.f, 0.f, 0.f, 0.f};
        if (valid) v = *(const float4*)(row + cbase + col);
        a += v.x * v.x + v.y * v.y + v.z * v.z + v.w * v.w;
        uint2 pk;
        pk.x = f2bf(v.x) | (f2bf(v.y) << 16);
        pk.y = f2bf(v.z) | (f2bf(v.w) << 16);
        *(uint2*)&Ls[r][col] = pk;
    }
    for (int o = 8; o; o >>= 1) a += __shfl_down(a, o, 16);
    if (q == 0 && a != 0.f) atomicAdd(&sqg[s0 + r], a);
    if (chunk == 0 && tid < 16) {
        int idx2 = idx0 + tid;
        bool v2 = idx2 < n;
        int g2 = v2 ? clsrows[(size_t)c * N + idx2] : 0;
        sgg[s0 + tid] = v2 ? ((g2 < ns) ? 1.f : -1.f) : 0.f;
    }
    __syncthreads();

    // classum: 2 dims per thread, sum over the 16 rows
    #pragma unroll
    for (int h = 0; h < 2; h++) {
        int d = h * 256 + tid;
        float s = 0.f;
        #pragma unroll
        for (int rr = 0; rr < 16; rr++)
            s += __uint_as_float((unsigned)Ls[rr][d] << 16);
        if (s != 0.f) atomicAdd(&classum[(size_t)c * D + cbase + d], s);
    }

    // fragment-major write: Xp[panel][k8 global][pr*8..+8]
    int pr = tid & 15, k8g = tid >> 4;
    size_t pb = (size_t)p * 32768;        // u16 per panel (256 k8 * 128)
    #pragma unroll
    for (int it = 0; it < 4; it++) {
        int k8l = k8g * 4 + it;
        uint4 val = *(uint4*)&Ls[pr][k8l * 8];
        *(uint4*)(Xp + pb + (size_t)(chunk * 64 + k8l) * 128 + pr * 8) = val;
    }
}

// ---- per-class bandwidth: sqsum from sqg, snorm from classum ----
__global__ void k_bw(const float* __restrict__ classum, const float* __restrict__ sqg,
                     const int* __restrict__ cnt_src, const int* __restrict__ fill,
                     int D, int C, float* __restrict__ invbw) {
    __shared__ int proS[65], tpoS[65], tS[64], presS[64], padTotS, nTilesS;
    scan_offsets2(cnt_src, fill, C, proS, tpoS, tS, presS, &padTotS, &nTilesS);
    int c = blockIdx.x;
    int tid = threadIdx.x;
    int n = fill[c], nsrc = cnt_src[c];
    int pres = (nsrc > 0 && (n - nsrc) > 0) ? 1 : 0;
    const float* cp = classum + (size_t)c * D;
    double sn = 0.0, sq = 0.0;
    for (int d = tid; d < D; d += 256) { double v = (double)cp[d]; sn += v * v; }
    for (int i = proS[c] + tid; i < proS[c + 1]; i += 256) sq += (double)sqg[i];
    for (int o = 32; o; o >>= 1) {
        sn += __shfl_down(sn, o);
        sq += __shfl_down(sq, o);
    }
    __shared__ double ls[4], ls2[4];
    if ((tid & 63) == 0) { ls[tid >> 6] = sn; ls2[tid >> 6] = sq; }
    __syncthreads();
    if (tid == 0) {
        double snorm = ls[0] + ls[1] + ls[2] + ls[3];
        double sqsum = ls2[0] + ls2[1] + ls2[2] + ls2[3];
        double l2 = 2.0 * (double)n * sqsum - 2.0 * snorm;
        double den = (double)n * (double)n - (double)n; if (den < 1.0) den = 1.0;
        double bw = l2 / den / 4.0;          // bw_scale = KERNEL_MUL^(KERNEL_NUM//2)
        bw = pres ? fmax(bw, 1e-20) : 1.0;
        double m = 1.0;
        for (int k = 0; k < 5; k++) { invbw[c * 5 + k] = (float)(1.0 / (bw * m)); m *= 2.0; }
    }
}

// ---- fused pair kernel: block = (class, ti<=tj tile); 4 waves split-K; in-block epi ----
__global__ __launch_bounds__(256) void k_pairs(
        const unsigned short* __restrict__ Xp, const float* __restrict__ sqg,
        const float* __restrict__ sgg, const float* __restrict__ invbw,
        const int* __restrict__ cnt_src, const int* __restrict__ fill,
        int N, int D, int C, double* __restrict__ contrib) {
    __shared__ int proS[65], tpoS[65], tS[64], presS[64], padTotS, nTilesS;
    scan_offsets2(cnt_src, fill, C, proS, tpoS, tS, presS, &padTotS, &nTilesS);
    __shared__ float Lp[4 * 16 * 64];        // [wv][frag fi*2+fj][r][lane] = 16 KB
    __shared__ float sqA[32], sgA[32], sqB[32], sgB[32];

    int tid = threadIdx.x, lane = tid & 63, wv = tid >> 6;
    int kgrp = lane >> 4, lr = lane & 15;
    int nTiles = nTilesS;

    for (int job = blockIdx.x; job < nTiles; job += gridDim.x) {
        __syncthreads();                      // protect LDS from previous job
        int c = __popcll(__ballot((lane < C) && (tpoS[lane] <= job))) - 1;
        int t = job - tpoS[c];
        int T = tS[c];
        int ti = 0, rem = t;
        while (rem >= T - ti) { rem -= (T - ti); ti++; }   // upper-triangle decode
        int tj = ti + rem;
        int pbase = proS[c];
        int n = fill[c];
        float wgt = (ti == tj) ? 1.f : 2.f;   // gram symmetry

        if (tid < 32) {
            sqA[tid] = sqg[pbase + ti * 32 + tid];
            sgA[tid] = sgg[pbase + ti * 32 + tid];
        } else if (tid < 64) {
            int j = tid - 32;
            sqB[j] = sqg[pbase + tj * 32 + j];
            sgB[j] = sgg[pbase + tj * 32 + j];
        }

        size_t pA0 = ((size_t)(pbase >> 4) + ti * 2) * 32768;   // u16 units
        size_t pA1 = pA0 + 32768;
        size_t pB0 = ((size_t)(pbase >> 4) + tj * 2) * 32768;
        size_t pB1 = pB0 + 32768;
        int k8base = wv * 64;                 // this wave's K-quarter (512 dims)

        f32x4 a00 = (f32x4){0.f, 0.f, 0.f, 0.f}, a01 = a00, a10 = a00, a11 = a00;
        #pragma unroll 4
        for (int ks = 0; ks < 16; ks++) {
            size_t off = (size_t)(k8base + ks * 4 + kgrp) * 128 + lr * 8;
            bf16x8 va0 = *(const bf16x8*)(Xp + pA0 + off);
            bf16x8 va1 = *(const bf16x8*)(Xp + pA1 + off);
            bf16x8 vb0 = *(const bf16x8*)(Xp + pB0 + off);
            bf16x8 vb1 = *(const bf16x8*)(Xp + pB1 + off);
            a00 = __builtin_amdgcn_mfma_f32_16x16x32_bf16(va0, vb0, a00, 0, 0, 0);
            a01 = __builtin_amdgcn_mfma_f32_16x16x32_bf16(va0, vb1, a01, 0, 0, 0);
            a10 = __builtin_amdgcn_mfma_f32_16x16x32_bf16(va1, vb0, a10, 0, 0, 0);
            a11 = __builtin_amdgcn_mfma_f32_16x16x32_bf16(va1, vb1, a11, 0, 0, 0);
        }
        #pragma unroll
        for (int r = 0; r < 4; r++) {
            Lp[((wv * 4 + 0) * 4 + r) * 64 + lane] = a00[r];
            Lp[((wv * 4 + 1) * 4 + r) * 64 + lane] = a01[r];
            Lp[((wv * 4 + 2) * 4 + r) * 64 + lane] = a10[r];
            Lp[((wv * 4 + 3) * 4 + r) * 64 + lane] = a11[r];
        }
        __syncthreads();

        float ib0 = invbw[c * 5 + 0], ib1 = invbw[c * 5 + 1], ib2 = invbw[c * 5 + 2];
        float ib3 = invbw[c * 5 + 3], ib4 = invbw[c * 5 + 4];
        int i = tid >> 3;                     // 0..31
        int j0 = (tid & 7) * 4;
        bool vi = (ti * 32 + i) < n;
        float sa = sqA[i], ga = sgA[i];
        float ts = 0.f;
        #pragma unroll
        for (int q = 0; q < 4; q++) {
            int j = j0 + q;
            bool vj = (tj * 32 + j) < n;
            int f = (i >> 4) * 2 + (j >> 4);
            int le = ((i & 15) >> 2) * 16 + (j & 15);   // m89 C/D layout
            int r = i & 3;
            float dot = Lp[((0 * 4 + f) * 4 + r) * 64 + le]
                      + Lp[((1 * 4 + f) * 4 + r) * 64 + le]
                      + Lp[((2 * 4 + f) * 4 + r) * 64 + le]
                      + Lp[((3 * 4 + f) * 4 + r) * 64 + le];
            if (vi && vj) {
                float D2 = sa + sqB[j] - 2.f * dot;
                float e = expf(-D2 * ib0) + expf(-D2 * ib1) + expf(-D2 * ib2)
                        + expf(-D2 * ib3) + expf(-D2 * ib4);
                ts += ga * sgB[j] * e;
            }
        }
        double ds = (double)(ts * wgt);
        for (int o = 32; o; o >>= 1) ds += __shfl_down(ds, o);
        if (lane == 0) atomicAdd(&contrib[c], ds);
    }
}

__global__ void k_final(const double* __restrict__ contrib,
                        const int* __restrict__ cnt_src, const int* __restrict__ fill,
                        int C, float* __restrict__ out) {
    int c = threadIdx.x;
    double l = 0.0, k = 0.0;
    if (c < C) {
        int n = fill[c], nsrc = cnt_src[c];
        if (nsrc > 0 && (n - nsrc) > 0) {
            double nn = (double)n * (double)n; if (nn < 1.0) nn = 1.0;
            l = contrib[c] / nn; k = 1.0;
        }
    }
    for (int o = 32; o; o >>= 1) { l += __shfl_down(l, o); k += __shfl_down(k, o); }
    if (c == 0) out[0] = (float)(l / k);
}

extern "C" void kernel_launch(void* const* d_in, const int* in_sizes, int n_in,
                              void* d_out, int out_size, void* d_ws, size_t ws_size,
                              hipStream_t stream) {
    const float* src  = (const float*)d_in[0];
    const float* tgt  = (const float*)d_in[1];
    const int*   slab = (const int*)d_in[2];
    const float* tlab = (const float*)d_in[3];
    const int ns = in_sizes[2];
    const int D  = in_sizes[0] / ns;
    const int nt = in_sizes[1] / D;
    const int C  = in_sizes[3] / nt;
    const int N  = ns + nt;
    const int padN = N + 32 * C;            // upper bound on padded slots

    char* w = (char*)d_ws;
    size_t off = 0;
    auto take = [&](size_t bytes) -> char* {
        char* p = w + off;
        off = (off + bytes + 255) & ~(size_t)255;
        return p;
    };
    // --- zero region (memset below) ---
    int*    cnt_src = (int*)take(64 * sizeof(int));
    int*    fill    = (int*)take(64 * sizeof(int));
    double* contrib = (double*)take(64 * sizeof(double));
    float*  classum = (float*)take((size_t)C * D * sizeof(float));
    float*  sqg     = (float*)take((size_t)padN * sizeof(float));
    size_t zbytes = off;
    // --- rest ---
    int*            clsrows = (int*)take((size_t)C * N * sizeof(int));
    float*          sgg     = (float*)take((size_t)padN * sizeof(float));
    float*          invbw   = (float*)take((size_t)C * 5 * sizeof(float));
    unsigned short* Xp      = (unsigned short*)take((size_t)padN * D * sizeof(unsigned short));
    (void)n_in; (void)out_size; (void)ws_size;

    hipMemsetAsync(d_ws, 0, zbytes, stream);
    k_prep<<<(N + 255) / 256, 256, 0, stream>>>(slab, tlab, ns, N, C, clsrows, cnt_src, fill);
    dim3 gg((padN + 15) / 16, 4);
    k_gather<<<gg, 256, 0, stream>>>(src, tgt, clsrows, cnt_src, fill,
                                     ns, N, D, C, Xp, sqg, sgg, classum);
    k_bw<<<C, 256, 0, stream>>>(classum, sqg, cnt_src, fill, D, C, invbw);
    k_pairs<<<1024, 256, 0, stream>>>(Xp, sqg, sgg, invbw, cnt_src, fill, N, D, C, contrib);
    k_final<<<1, 64, 0, stream>>>(contrib, cnt_src, fill, C, (float*)d_out);
}